// Round 2
// baseline (302.308 us; speedup 1.0000x reference)
//
#include <hip/hip_runtime.h>

// MVDR oracle beamformer — MI355X (gfx950)
// Phase A (R2 rewrite): per-(n,f) Hermitian covariance partial sums.
//   R0/R1 evidence: two different load mechanisms (VGPR JIT, LDS-DMA ring)
//   both landed ~80 µs at ~2 TB/s -> per-CU memory-level parallelism is the
//   invariant bottleneck (7.8 single-wave blocks/CU, ~1-2 loads in flight
//   each; LLVM also inserts vmcnt(0) before ds_read aliasing global_load_lds).
//   Fix: 256-thread blocks (800 of them), LDS double-buffered t-slab staged
//   via plain VGPR loads + ds_write (issue-early / write-late: the vmcnt wait
//   lands after the compute block). ~25 KB in flight per CU by construction.
// Phase B1: float4 parallel reduction of the t-chunks (into chunk-0 slot).
// Phase B2: streaming solve — invert phi_v (unpivoted GJ, diag-dominant),
//           build W = conj(H).
// Phase C: beamform X = sum_c W[c] * y[c].

constexpr int N_  = 8;
constexpr int C_  = 8;
constexpr int T_  = 600;
constexpr int F_  = 257;
constexpr int TF_  = T_ * F_;       // 154200
constexpr int CTF_ = C_ * TF_;      // 1233600
constexpr int NSTR_ = 2 * CTF_;     // per-batch stride in inputs
constexpr int NF_  = N_ * F_;       // 2056
constexpr int NPAIR_ = 36;          // lower-triangle pairs of 8x8 Hermitian
constexpr float LOADC_ = 7.0710678118654755e-4f;  // 0.001/sqrt(2)
constexpr float INV_T_ = 1.0f / 600.0f;

struct cx { float r, i; };
__device__ __forceinline__ cx cmul(cx a, cx b) { return {a.r*b.r - a.i*b.i, a.r*b.i + a.i*b.r}; }
__device__ __forceinline__ cx csub(cx a, cx b) { return {a.r - b.r, a.i - b.i}; }
__device__ __forceinline__ cx cconj(cx a) { return {a.r, -a.i}; }
__device__ __forceinline__ cx cinv(cx a) {
    float id = 1.0f / (a.r*a.r + a.i*a.i);
    return {a.r*id, -a.i*id};
}
__device__ __forceinline__ cx cmadd(cx acc, cx a, cx b) {
    acc.r += a.r*b.r - a.i*b.i;
    acc.i += a.r*b.i + a.i*b.r;
    return acc;
}

// ---------------------------------------------------------------------------
// Phase A: partial covariance sums.
// grid (2, N, 2*TSPLIT), block 256 (4 waves).
//   blockIdx.x = f-half (fbase 0 width 128 | fbase 128 width 129)
//   blockIdx.y = n ; blockIdx.z: m = z&1 (0 noise, 1 mixture), chunk = z>>1
// Per t-step: stage 16 rows (c,ri) x width floats into LDS (dbuf), each
// compute thread (tid < width) owns one f and updates 36 Hermitian pairs.
// Staging role: half-wave hw = tid>>5 stages rows {hw, hw+8}, lane l covers
// cols {l, l+32, l+64, l+96} (+ col 128 by lane 0 when width==129) ->
// 128 B contiguous per half-wave segment, fully coalesced.
// Partial layout (unchanged): part[((m*TSPLIT+chunk)*72 + 2p+ri)*NF + n*F + f]
// ---------------------------------------------------------------------------
template<int TSPLIT>
__global__ __launch_bounds__(256, 3) void cov_partial(
        const float* __restrict__ mix, const float* __restrict__ noi,
        float* __restrict__ part) {
    constexpr int TCHUNK = T_ / TSPLIT;

    __shared__ float S[2][16][132];   // [buf][row=2c+ri][f-local]  16.9 KB

    const int tid = threadIdx.x;
    const int hw  = tid >> 5;         // half-wave 0..7
    const int l   = tid & 31;
    const int fh    = blockIdx.x;
    const int fbase = fh * 128;
    const int FW    = fh ? (F_ - 128) : 128;   // 129 | 128
    const int n = blockIdx.y;
    const int z = blockIdx.z;
    const int m = z & 1;
    const int chunk = z >> 1;

    const float* src = (m ? mix : noi) + (size_t)n * NSTR_
                     + (size_t)(chunk * TCHUNK) * F_ + fbase;

    // Plane offsets for this thread's two staging rows r = hw, hw+8.
    size_t poff0, poff1;
    {
        const int r0 = hw, r1 = hw + 8;
        poff0 = (size_t)(r0 >> 1) * TF_ + (size_t)(r0 & 1) * CTF_;
        poff1 = (size_t)(r1 >> 1) * TF_ + (size_t)(r1 & 1) * CTF_;
    }

    float rg[2][4], tl[2];
    auto stage = [&](int t) {   // issue global loads into registers
        const float* row0 = src + poff0 + (size_t)t * F_;
        const float* row1 = src + poff1 + (size_t)t * F_;
#pragma unroll
        for (int k = 0; k < 4; ++k) {
            rg[0][k] = row0[l + 32*k];
            rg[1][k] = row1[l + 32*k];
        }
        if (FW == 129 && l == 0) { tl[0] = row0[128]; tl[1] = row1[128]; }
    };
    auto write_lds = [&](int buf) {   // vmcnt wait lands here, after compute
        const int r0 = hw, r1 = hw + 8;
#pragma unroll
        for (int k = 0; k < 4; ++k) {
            S[buf][r0][l + 32*k] = rg[0][k];
            S[buf][r1][l + 32*k] = rg[1][k];
        }
        if (FW == 129 && l == 0) { S[buf][r0][128] = tl[0]; S[buf][r1][128] = tl[1]; }
    };

    float accr[NPAIR_], acci[NPAIR_];
#pragma unroll
    for (int p = 0; p < NPAIR_; ++p) { accr[p] = 0.f; acci[p] = 0.f; }

    auto consume = [&](int buf) {
        if (tid < FW) {
            float re[C_], im[C_];
#pragma unroll
            for (int c = 0; c < C_; ++c) {
                re[c] = S[buf][2*c][tid];       // stride-4B across lanes: free
                im[c] = S[buf][2*c+1][tid];
            }
            int p = 0;
#pragma unroll
            for (int c = 0; c < C_; ++c) {
#pragma unroll
                for (int d = 0; d <= c; ++d, ++p) {
                    accr[p] += re[c]*re[d] + im[c]*im[d];
                    acci[p] += im[c]*re[d] - re[c]*im[d];
                }
            }
        }
    };

    // Prologue: fill buffer 0.
    stage(0);
    write_lds(0);
    __syncthreads();

    for (int t = 0; t < TCHUNK; ++t) {
        const int cur = t & 1;
        const bool more = (t + 1 < TCHUNK);
        if (more) stage(t + 1);      // loads issue before compute
        consume(cur);                // LDS reads + FMAs hide load latency
        if (more) write_lds(cur ^ 1);
        __syncthreads();             // one barrier per t-step
    }

    if (tid < FW) {
        const int f = fbase + tid;
        float* out = part + (size_t)((m * TSPLIT + chunk) * 72) * NF_ + n * F_ + f;
#pragma unroll
        for (int p = 0; p < NPAIR_; ++p) {
            out[(size_t)(2*p)   * NF_] = accr[p];
            out[(size_t)(2*p+1) * NF_] = acci[p];
        }
    }
}

// ---------------------------------------------------------------------------
// Phase B1: reduce the chunks into the chunk-0 slot, float4-vectorized.
// One thread per (m, q, idx4): 2*72*514 = 74016 threads. All strides are
// multiples of NF_ floats = 8224 B (16B-aligned), idx4*16 B aligned.
// ---------------------------------------------------------------------------
__global__ __launch_bounds__(256) void reduce_cov(float* __restrict__ part, int tsplit) {
    int flat = blockIdx.x * 256 + threadIdx.x;
    constexpr int NQ4 = NF_ / 4;   // 514
    if (flat >= 2 * 72 * NQ4) return;
    int idx4 = flat % NQ4;
    int z = flat / NQ4;          // z = m*72 + q
    int m = z / 72;
    int q = z % 72;
    const float4* p4 = (const float4*)(part) + ((size_t)((m * tsplit) * 72 + q) * NF_) / 4 + idx4;
    float4 s = {0.f, 0.f, 0.f, 0.f};
    for (int ch = 0; ch < tsplit; ++ch) {
        float4 v = p4[(size_t)(ch * 72) * NF_ / 4];
        s.x += v.x; s.y += v.y; s.z += v.z; s.w += v.w;
    }
    *(float4*)((float*)part + (size_t)((m * tsplit) * 72 + q) * NF_ + idx4 * 4) = s;
}

// ---------------------------------------------------------------------------
// Phase B2: streaming solve. One thread per (n,f). yBase = tsplit*72*NF_.
// ---------------------------------------------------------------------------
__global__ __launch_bounds__(64, 1) void solve_w(
        const float* __restrict__ part, float* __restrict__ W, size_t yBase) {
    int idx = blockIdx.x * 64 + threadIdx.x;  // idx = n*F + f
    if (idx >= NF_) return;

    const float* pv = part + idx;            // m=0, chunk 0
    const float* py = part + yBase + idx;    // m=1, chunk 0

    // Build M = phi_v/T + LOAD*(1+i)*I directly from loads.
    cx M[64];
#pragma unroll
    for (int c = 0; c < 8; ++c) {
#pragma unroll
        for (int d = 0; d <= c; ++d) {
            int p = c*(c+1)/2 + d;
            cx val = { pv[(size_t)(2*p) * NF_] * INV_T_,
                       pv[(size_t)(2*p+1) * NF_] * INV_T_ };
            if (d == c) { val.r += LOADC_; val.i += LOADC_; }
            M[c*8 + d] = val;
            if (d < c) M[d*8 + c] = cconj(val);
        }
    }

    // In-place Gauss-Jordan inverse, no pivoting (diagonally dominant).
#pragma unroll
    for (int k = 0; k < 8; ++k) {
        cx p = cinv(M[k*8 + k]);
        M[k*8 + k] = p;
#pragma unroll
        for (int j = 0; j < 8; ++j) {
            if (j != k) M[k*8 + j] = cmul(M[k*8 + j], p);
        }
#pragma unroll
        for (int i = 0; i < 8; ++i) {
            if (i == k) continue;
            cx fkt = M[i*8 + k];
#pragma unroll
            for (int j = 0; j < 8; ++j) {
                if (j != k) M[i*8 + j] = csub(M[i*8 + j], cmul(fkt, M[k*8 + j]));
            }
            cx t = cmul(fkt, p);
            M[i*8 + k] = { -t.r, -t.i };
        }
    }

    // Stream the 36 stored y-pairs: yv = phi_y[a][b] (a >= b), scaled by 1/T.
    cx tr = {0.f, 0.f};
    cx g0[8];
#pragma unroll
    for (int c = 0; c < 8; ++c) g0[c] = (cx){0.f, 0.f};

#pragma unroll
    for (int a = 0; a < 8; ++a) {
#pragma unroll
        for (int b = 0; b <= a; ++b) {
            int p = a*(a+1)/2 + b;
            cx yv = { py[(size_t)(2*p) * NF_] * INV_T_,
                      py[(size_t)(2*p+1) * NF_] * INV_T_ };
            tr = cmadd(tr, M[b*8 + a], yv);
            if (a != b) tr = cmadd(tr, M[a*8 + b], cconj(yv));
            if (b == 0) {
#pragma unroll
                for (int i = 0; i < 8; ++i) g0[i] = cmadd(g0[i], M[i*8 + a], yv);
            }
        }
    }

    cx l = { tr.r - 8.0f, tr.i - 8.0f };
    float iden = 1.0f / (l.r*l.r + l.i*l.i);

    float* w = W + (size_t)idx * 16;
#pragma unroll
    for (int c = 0; c < 8; ++c) {
        cx ge = g0[c];
        if (c == 0) ge.r -= 1.0f;
        // W = conj(H) = conj(ge) * l / |l|^2
        w[2*c]     = (ge.r*l.r + ge.i*l.i) * iden;
        w[2*c + 1] = (ge.r*l.i - ge.i*l.r) * iden;
    }
}

// ---------------------------------------------------------------------------
// Phase C: beamform. grid (ceil(TF/256), N), block 256. Thread owns flat j=t*F+f.
// ---------------------------------------------------------------------------
__global__ __launch_bounds__(256) void beamform(
        const float* __restrict__ mix, const float* __restrict__ W,
        float* __restrict__ out) {
    int n = blockIdx.y;
    int j = blockIdx.x * 256 + threadIdx.x;
    if (j >= TF_) return;
    int f = j % F_;

    const float4* w4 = (const float4*)(W + (size_t)(n * F_ + f) * 16);
    float4 q0 = w4[0], q1 = w4[1], q2 = w4[2], q3 = w4[3];
    float wv[16] = { q0.x, q0.y, q0.z, q0.w,
                     q1.x, q1.y, q1.z, q1.w,
                     q2.x, q2.y, q2.z, q2.w,
                     q3.x, q3.y, q3.z, q3.w };

    const float* base = mix + (size_t)n * NSTR_ + j;
    float xr = 0.f, xi = 0.f;
#pragma unroll
    for (int c = 0; c < C_; ++c) {
        float yr = base[(size_t)c * TF_];
        float yi = base[(size_t)c * TF_ + CTF_];
        float wr = wv[2*c], wi = wv[2*c + 1];
        xr += wr*yr - wi*yi;
        xi += wr*yi + wi*yr;
    }
    float* op = out + (size_t)n * (2 * TF_);
    op[j]       = xr;
    op[TF_ + j] = xi;
}

extern "C" void kernel_launch(void* const* d_in, const int* in_sizes, int n_in,
                              void* d_out, int out_size, void* d_ws, size_t ws_size,
                              hipStream_t stream) {
    const float* mix = (const float*)d_in[0];
    // d_in[1] = target, unused by the reference
    const float* noi = (const float*)d_in[2];

    // TSPLIT=25 needs 2*25*72*NF + 16*NF floats of scratch (~29.7 MB).
    const size_t need25 = ((size_t)2 * 25 * 72 * NF_ + (size_t)16 * NF_) * 4;
    float* part = (float*)d_ws;
    int tsplit;
    if (ws_size >= need25) {
        tsplit = 25;   // TCHUNK=24: 800 blocks x 4 waves ≈ 3.1 blocks/CU
        cov_partial<25><<<dim3(2, N_, 2 * 25), 256, 0, stream>>>(mix, noi, part);
    } else {
        tsplit = 20;   // fallback, TCHUNK=30
        cov_partial<20><<<dim3(2, N_, 2 * 20), 256, 0, stream>>>(mix, noi, part);
    }
    float* W = part + (size_t)2 * tsplit * 72 * NF_;

    reduce_cov<<<dim3((2 * 72 * (NF_ / 4) + 255) / 256), 256, 0, stream>>>(part, tsplit);
    solve_w<<<dim3((NF_ + 63) / 64), 64, 0, stream>>>(part, W, (size_t)tsplit * 72 * NF_);
    beamform<<<dim3((TF_ + 255) / 256, N_), 256, 0, stream>>>(mix, W, (float*)d_out);
}

// Round 4
// 277.371 us; speedup vs baseline: 1.0899x; 1.0899x over previous
//
#include <hip/hip_runtime.h>

// MVDR oracle beamformer — MI355X (gfx950)
// Phase A (R4): register-pipelined covariance partials with PINNED schedule
//   via __builtin_amdgcn_sched_barrier(0) (R3's sched_group_barrier variant
//   died in the harness, likely an IGroupLP compiler crash; sched_barrier is
//   the proven-safe primitive, learn_hip m141).
//   Root cause across R0/R1/R2 (VGPR evidence 96/132/68): hipcc sinks global
//   loads to first use, collapsing every source-level pipeline -> ~2 KB in
//   flight/wave -> latency-bound at 1.2-2 TB/s. sched_barrier(0) after each
//   16-load refill makes each t-step its own scheduling region: loads cannot
//   sink past the barrier, so the PIPE=4 ring (64 loads = 16 KB/wave in
//   flight) stays architecturally live. No LDS => no DMA-alias vmcnt(0)
//   pathology, no barriers, no LDS pipe cost.
// Phase B1: float4 parallel reduction of the t-chunks (into chunk-0 slot).
// Phase B2: streaming solve — invert phi_v (unpivoted GJ, diag-dominant).
// Phase C: beamform X = sum_c W[c] * y[c].

constexpr int N_  = 8;
constexpr int C_  = 8;
constexpr int T_  = 600;
constexpr int F_  = 257;
constexpr int TF_  = T_ * F_;       // 154200
constexpr int CTF_ = C_ * TF_;      // 1233600
constexpr int NSTR_ = 2 * CTF_;     // per-batch stride in inputs
constexpr int NF_  = N_ * F_;       // 2056
constexpr int NPAIR_ = 36;          // lower-triangle pairs of 8x8 Hermitian
constexpr float LOADC_ = 7.0710678118654755e-4f;  // 0.001/sqrt(2)
constexpr float INV_T_ = 1.0f / 600.0f;

#define SBAR() __builtin_amdgcn_sched_barrier(0)

struct cx { float r, i; };
__device__ __forceinline__ cx cmul(cx a, cx b) { return {a.r*b.r - a.i*b.i, a.r*b.i + a.i*b.r}; }
__device__ __forceinline__ cx csub(cx a, cx b) { return {a.r - b.r, a.i - b.i}; }
__device__ __forceinline__ cx cconj(cx a) { return {a.r, -a.i}; }
__device__ __forceinline__ cx cinv(cx a) {
    float id = 1.0f / (a.r*a.r + a.i*a.i);
    return {a.r*id, -a.i*id};
}
__device__ __forceinline__ cx cmadd(cx acc, cx a, cx b) {
    acc.r += a.r*b.r - a.i*b.i;
    acc.i += a.r*b.i + a.i*b.r;
    return acc;
}

// ---------------------------------------------------------------------------
// Phase A: partial covariance sums, register ring PIPE=4, schedule pinned.
// grid (5, N, 2*TSPLIT), block 64 (1 wave). Thread owns one f; z&1 selects
// source (0 = noise -> phi_v, 1 = mixture -> phi_y); z>>1 selects t-chunk.
// Partial layout: part[((m*TSPLIT + chunk)*72 + (2p+ri)) * NF + n*F + f]
// No LDS, no barriers; lanes with f >= F_ exit immediately (no sync hazards).
// ---------------------------------------------------------------------------
template<int TSPLIT>
__global__ __launch_bounds__(64, 1) void cov_partial(
        const float* __restrict__ mix, const float* __restrict__ noi,
        float* __restrict__ part) {
    constexpr int TCHUNK = T_ / TSPLIT;
    constexpr int PIPE = 4;
    static_assert(TCHUNK > PIPE, "pipeline deeper than chunk");

    int f = blockIdx.x * 64 + threadIdx.x;
    if (f >= F_) return;
    int n = blockIdx.y;
    int z = blockIdx.z;
    int m = z & 1;
    int chunk = z >> 1;
    const float* src = m ? mix : noi;
    const float* pt = src + (size_t)n * NSTR_ + f + (size_t)(chunk * TCHUNK) * F_;

    float reB[PIPE][C_], imB[PIPE][C_];
    // Prologue: fill PIPE slots (64 loads issued before any consumption);
    // the barrier stops anything from hoisting above / loads sinking below.
#pragma unroll
    for (int s = 0; s < PIPE; ++s) {
        const float* pn = pt + (size_t)s * F_;
#pragma unroll
        for (int c = 0; c < C_; ++c) {
            reB[s][c] = pn[(size_t)c * TF_];
            imB[s][c] = pn[(size_t)c * TF_ + CTF_];
        }
    }
    SBAR();

    float accr[NPAIR_], acci[NPAIR_];
#pragma unroll
    for (int p = 0; p < NPAIR_; ++p) { accr[p] = 0.f; acci[p] = 0.f; }

#pragma unroll
    for (int tt = 0; tt < TCHUNK; ++tt) {
        const int s = tt % PIPE;
        const bool refill = (tt + PIPE < TCHUNK);

        // Copy slot s to locals (register rename; WAR deps keep this correct
        // w.r.t. the refill below), then refill slot s, then PIN: the 16 new
        // loads cannot sink past the sched_barrier into / beyond the FMA
        // block. Worst-case in-window placement still leaves slot-s loads
        // >= 3 FMA blocks ahead of their consumption (ring depth 3-4).
        float re[C_], im[C_];
#pragma unroll
        for (int c = 0; c < C_; ++c) { re[c] = reB[s][c]; im[c] = imB[s][c]; }

        if (refill) {
            const float* pn = pt + (size_t)(tt + PIPE) * F_;
#pragma unroll
            for (int c = 0; c < C_; ++c) {
                reB[s][c] = pn[(size_t)c * TF_];
                imB[s][c] = pn[(size_t)c * TF_ + CTF_];
            }
            SBAR();
        }

        int p = 0;
#pragma unroll
        for (int c = 0; c < C_; ++c) {
#pragma unroll
            for (int d = 0; d <= c; ++d, ++p) {
                accr[p] += re[c]*re[d] + im[c]*im[d];
                acci[p] += im[c]*re[d] - re[c]*im[d];
            }
        }
    }

    float* out = part + (size_t)((m * TSPLIT + chunk) * 72) * NF_ + n * F_ + f;
#pragma unroll
    for (int p = 0; p < NPAIR_; ++p) {
        out[(size_t)(2*p)   * NF_] = accr[p];
        out[(size_t)(2*p+1) * NF_] = acci[p];
    }
}

// ---------------------------------------------------------------------------
// Phase B1: reduce the chunks into the chunk-0 slot, float4-vectorized.
// One thread per (m, q, idx4): 2*72*514 = 74016 threads. All strides are
// multiples of NF_ floats = 8224 B (16B-aligned), idx4*16 B aligned.
// ---------------------------------------------------------------------------
__global__ __launch_bounds__(256) void reduce_cov(float* __restrict__ part, int tsplit) {
    int flat = blockIdx.x * 256 + threadIdx.x;
    constexpr int NQ4 = NF_ / 4;   // 514
    if (flat >= 2 * 72 * NQ4) return;
    int idx4 = flat % NQ4;
    int z = flat / NQ4;          // z = m*72 + q
    int m = z / 72;
    int q = z % 72;
    const float4* p4 = (const float4*)(part) + ((size_t)((m * tsplit) * 72 + q) * NF_) / 4 + idx4;
    float4 s = {0.f, 0.f, 0.f, 0.f};
    for (int ch = 0; ch < tsplit; ++ch) {
        float4 v = p4[(size_t)(ch * 72) * NF_ / 4];
        s.x += v.x; s.y += v.y; s.z += v.z; s.w += v.w;
    }
    *(float4*)((float*)part + (size_t)((m * tsplit) * 72 + q) * NF_ + idx4 * 4) = s;
}

// ---------------------------------------------------------------------------
// Phase B2: streaming solve. One thread per (n,f). yBase = tsplit*72*NF_.
// ---------------------------------------------------------------------------
__global__ __launch_bounds__(64, 1) void solve_w(
        const float* __restrict__ part, float* __restrict__ W, size_t yBase) {
    int idx = blockIdx.x * 64 + threadIdx.x;  // idx = n*F + f
    if (idx >= NF_) return;

    const float* pv = part + idx;            // m=0, chunk 0
    const float* py = part + yBase + idx;    // m=1, chunk 0

    // Build M = phi_v/T + LOAD*(1+i)*I directly from loads.
    cx M[64];
#pragma unroll
    for (int c = 0; c < 8; ++c) {
#pragma unroll
        for (int d = 0; d <= c; ++d) {
            int p = c*(c+1)/2 + d;
            cx val = { pv[(size_t)(2*p) * NF_] * INV_T_,
                       pv[(size_t)(2*p+1) * NF_] * INV_T_ };
            if (d == c) { val.r += LOADC_; val.i += LOADC_; }
            M[c*8 + d] = val;
            if (d < c) M[d*8 + c] = cconj(val);
        }
    }

    // In-place Gauss-Jordan inverse, no pivoting (diagonally dominant).
#pragma unroll
    for (int k = 0; k < 8; ++k) {
        cx p = cinv(M[k*8 + k]);
        M[k*8 + k] = p;
#pragma unroll
        for (int j = 0; j < 8; ++j) {
            if (j != k) M[k*8 + j] = cmul(M[k*8 + j], p);
        }
#pragma unroll
        for (int i = 0; i < 8; ++i) {
            if (i == k) continue;
            cx fkt = M[i*8 + k];
#pragma unroll
            for (int j = 0; j < 8; ++j) {
                if (j != k) M[i*8 + j] = csub(M[i*8 + j], cmul(fkt, M[k*8 + j]));
            }
            cx t = cmul(fkt, p);
            M[i*8 + k] = { -t.r, -t.i };
        }
    }

    // Stream the 36 stored y-pairs: yv = phi_y[a][b] (a >= b), scaled by 1/T.
    cx tr = {0.f, 0.f};
    cx g0[8];
#pragma unroll
    for (int c = 0; c < 8; ++c) g0[c] = (cx){0.f, 0.f};

#pragma unroll
    for (int a = 0; a < 8; ++a) {
#pragma unroll
        for (int b = 0; b <= a; ++b) {
            int p = a*(a+1)/2 + b;
            cx yv = { py[(size_t)(2*p) * NF_] * INV_T_,
                      py[(size_t)(2*p+1) * NF_] * INV_T_ };
            tr = cmadd(tr, M[b*8 + a], yv);
            if (a != b) tr = cmadd(tr, M[a*8 + b], cconj(yv));
            if (b == 0) {
#pragma unroll
                for (int i = 0; i < 8; ++i) g0[i] = cmadd(g0[i], M[i*8 + a], yv);
            }
        }
    }

    cx l = { tr.r - 8.0f, tr.i - 8.0f };
    float iden = 1.0f / (l.r*l.r + l.i*l.i);

    float* w = W + (size_t)idx * 16;
#pragma unroll
    for (int c = 0; c < 8; ++c) {
        cx ge = g0[c];
        if (c == 0) ge.r -= 1.0f;
        // W = conj(H) = conj(ge) * l / |l|^2
        w[2*c]     = (ge.r*l.r + ge.i*l.i) * iden;
        w[2*c + 1] = (ge.r*l.i - ge.i*l.r) * iden;
    }
}

// ---------------------------------------------------------------------------
// Phase C: beamform. grid (ceil(TF/256), N), block 256. Thread owns flat j=t*F+f.
// ---------------------------------------------------------------------------
__global__ __launch_bounds__(256) void beamform(
        const float* __restrict__ mix, const float* __restrict__ W,
        float* __restrict__ out) {
    int n = blockIdx.y;
    int j = blockIdx.x * 256 + threadIdx.x;
    if (j >= TF_) return;
    int f = j % F_;

    const float4* w4 = (const float4*)(W + (size_t)(n * F_ + f) * 16);
    float4 q0 = w4[0], q1 = w4[1], q2 = w4[2], q3 = w4[3];
    float wv[16] = { q0.x, q0.y, q0.z, q0.w,
                     q1.x, q1.y, q1.z, q1.w,
                     q2.x, q2.y, q2.z, q2.w,
                     q3.x, q3.y, q3.z, q3.w };

    const float* base = mix + (size_t)n * NSTR_ + j;
    float xr = 0.f, xi = 0.f;
#pragma unroll
    for (int c = 0; c < C_; ++c) {
        float yr = base[(size_t)c * TF_];
        float yi = base[(size_t)c * TF_ + CTF_];
        float wr = wv[2*c], wi = wv[2*c + 1];
        xr += wr*yr - wi*yi;
        xi += wr*yi + wi*yr;
    }
    float* op = out + (size_t)n * (2 * TF_);
    op[j]       = xr;
    op[TF_ + j] = xi;
}

extern "C" void kernel_launch(void* const* d_in, const int* in_sizes, int n_in,
                              void* d_out, int out_size, void* d_ws, size_t ws_size,
                              hipStream_t stream) {
    const float* mix = (const float*)d_in[0];
    // d_in[1] = target, unused by the reference
    const float* noi = (const float*)d_in[2];

    // TSPLIT=25 needs 2*25*72*NF + 16*NF floats of scratch (~29.7 MB).
    const size_t need25 = ((size_t)2 * 25 * 72 * NF_ + (size_t)16 * NF_) * 4;
    float* part = (float*)d_ws;
    int tsplit;
    if (ws_size >= need25) {
        tsplit = 25;   // TCHUNK=24, PIPE=4: 2000 waves, ~8/CU (all resident)
        cov_partial<25><<<dim3(5, N_, 2 * 25), 64, 0, stream>>>(mix, noi, part);
    } else {
        tsplit = 15;   // fallback, TCHUNK=40
        cov_partial<15><<<dim3(5, N_, 2 * 15), 64, 0, stream>>>(mix, noi, part);
    }
    float* W = part + (size_t)2 * tsplit * 72 * NF_;

    reduce_cov<<<dim3((2 * 72 * (NF_ / 4) + 255) / 256), 256, 0, stream>>>(part, tsplit);
    solve_w<<<dim3((NF_ + 63) / 64), 64, 0, stream>>>(part, W, (size_t)tsplit * 72 * NF_);
    beamform<<<dim3((TF_ + 255) / 256, N_), 256, 0, stream>>>(mix, W, (float*)d_out);
}